// Round 10
// baseline (1149.334 us; speedup 1.0000x reference)
//
#include <hip/hip_runtime.h>

typedef __attribute__((ext_vector_type(4))) float f32x4;
typedef __attribute__((ext_vector_type(8))) _Float16 f16x8;
typedef __attribute__((ext_vector_type(4))) _Float16 f16x4;
typedef unsigned short u16;
typedef unsigned int u32;
typedef unsigned long long u64;

#define XGCAP 34304           // rows with stored xg/hq (non-reset ~32832, 12-sigma margin)
#define TRASH (XGCAP - 1)     // dump row for successors that don't exist
#define NXG 4096              // xg tiles: 1024 tm x 4 jp

__device__ __forceinline__ float sigm(float v){ return 1.0f / (1.0f + __expf(-v)); }
__device__ __forceinline__ float tanh_fast(float v){
  v = fminf(15.0f, fmaxf(-15.0f, v));
  float e = __expf(2.0f * v);
  return (e - 1.0f) / (e + 1.0f);
}
// agent-scope atomics: coherent at L3, no cache-invalidating fences
__device__ __forceinline__ double aload(const double* p){
  return __hip_atomic_load(p, __ATOMIC_RELAXED, __HIP_MEMORY_SCOPE_AGENT);
}
__device__ __forceinline__ void astore64(u64* p, u64 v){
  __hip_atomic_store(p, v, __ATOMIC_RELAXED, __HIP_MEMORY_SCOPE_AGENT);
}
__device__ __forceinline__ u32 apoll(const u32* p){
  return __hip_atomic_load(p, __ATOMIC_RELAXED, __HIP_MEMORY_SCOPE_AGENT);
}
__device__ __forceinline__ void abump(u32* p, u32 v){
  __hip_atomic_fetch_add(p, v, __ATOMIC_RELAXED, __HIP_MEMORY_SCOPE_AGENT);
}

// ---------------------------------------------------------------------------
// P1 v3: depth-ordered row lists, EACH LEVEL SORTED BY (b, t). Sorting makes
// the succ map between consecutive levels a monotone injection -> a consumer
// tile's producers form a narrow window in the previous level -> the scan
// pipelines across levels instead of behaving like a level barrier.
// Placement: per-(level,b) counts in LDS u16 (levels <127; atomic fallback
// deeper), prefix over b per level, deterministic positions.
// rows[] entry: t | b<<9 | fl<<16  (0=wait-on-producer, 1=xg-handled, 2=h0).
// ---------------------------------------------------------------------------
__global__ __launch_bounds__(512) void prep_lists(
    const void* __restrict__ resets_raw, const float* __restrict__ h0,
    u32* __restrict__ rows, u32* __restrict__ off, int* __restrict__ nlists,
    u32* __restrict__ succ, _Float16* __restrict__ hq)
{
  __shared__ u32 bitmap[2048];      // 65536 bits, bit = t*128+b
  __shared__ u16 lcnt[127*128];     // per-(level<127, b) counts -> cursors
  __shared__ u32 cnt[520];
  __shared__ u32 offs[521];
  __shared__ u32 cur[520];          // tail (level>=127) cursors
  __shared__ int is_bytes, h0nz;
  const int tid = threadIdx.x;
  const int lane = tid & 63, wave = tid >> 6;
  for (int i = tid; i < 2048; i += 512) bitmap[i] = 0;
  for (int i = tid; i < 127*128; i += 512) lcnt[i] = 0;
  for (int i = tid; i < 520; i += 512){ cnt[i] = 0; cur[i] = 0; }
  if (tid == 0){ is_bytes = 0; h0nz = 0; }
  for (int i = tid; i < 64; i += 512){ rows[65536 + i] = (2u << 16); succ[65536 + i] = TRASH; }
  __syncthreads();
  { // resets dtype sniff
    const u32* w = (const u32*)resets_raw;
    int bad = 0;
    for (int i = tid; i < 4096; i += 512) bad |= (w[i] > 1u);
    if (bad) atomicOr(&is_bytes, 1);
  }
  { // h0 == 0 sniff
    const u32* hw = (const u32*)h0;
    u32 o = 0;
    for (int i = tid; i < 65536; i += 512) o |= hw[i];
    if (o) atomicOr(&h0nz, 1);
  }
  __syncthreads();
  const bool h0zero = (h0nz == 0);
  if (is_bytes){
    const u32* wb = (const u32*)resets_raw;
    for (int i = tid; i < 16384; i += 512){
      u32 v = wb[i];
      u32 bits = ((v & 0xFFu) ? 1u : 0u) | (((v >> 8) & 0xFFu) ? 2u : 0u)
               | (((v >> 16) & 0xFFu) ? 4u : 0u) | (((v >> 24) & 0xFFu) ? 8u : 0u);
      if (bits) atomicOr(&bitmap[i >> 3], bits << ((i & 7) * 4));
    }
  } else {
    const u32* w = (const u32*)resets_raw;
    for (int r = 0; r < 128; ++r){
      u32 v = w[r * 512 + tid];
      u64 m = __ballot(v != 0u);
      if (lane == 0){
        int idx = r * 16 + wave * 2;
        bitmap[idx] = (u32)m; bitmap[idx + 1] = (u32)(m >> 32);
      }
    }
  }
  __syncthreads();
  // pass1: per-(li,b) counts (no contention: column per thread)
  if (tid < 128){
    const int b = tid;
    int depth = 0;
    for (int t = 0; t < 512; ++t){
      int pos = t * 128 + b;
      bool rs = (bitmap[pos >> 5] >> (pos & 31)) & 1u;
      depth = rs ? 0 : ((t == 0) ? 0 : depth + 1);
      int li = (depth == 0) ? ((rs || h0zero) ? 0 : 1) : (depth + 1);
      if (li < 127) lcnt[li*128 + b]++;
      else atomicAdd(&cnt[li], 1u);
    }
  }
  __syncthreads();
  // per-level totals + exclusive prefix over b (thread li handles level li)
  if (tid < 127){
    const int li = tid;
    u32 s = 0;
    for (int b = 0; b < 128; ++b){
      u32 v = lcnt[li*128 + b];
      lcnt[li*128 + b] = (u16)s;
      s += v;
    }
    cnt[li] = s;
  }
  __syncthreads();
  if (tid == 0){
    u32 s = 0; int mx = 0;
    for (int i = 0; i < 520; ++i){
      offs[i] = s; s += cnt[i];
      if (cnt[i]) mx = i;
    }
    offs[520] = s;
    *nlists = mx + 1;
  }
  __syncthreads();
  for (int i = tid; i < 521; i += 512) off[i] = offs[i];
  __syncthreads();
  const u32 n0 = offs[1];
  // pass2: deterministic sorted placement (lcnt now cursors) + succ
  if (tid < 128){
    const int b = tid;
    int depth = 0;
    u32 prev_p = 0;
    for (int t = 0; t < 512; ++t){
      int pos = t * 128 + b;
      bool rs = (bitmap[pos >> 5] >> (pos & 31)) & 1u;
      depth = rs ? 0 : ((t == 0) ? 0 : depth + 1);
      int li = (depth == 0) ? ((rs || h0zero) ? 0 : 1) : (depth + 1);
      u32 p;
      if (li < 127){
        u16 c = lcnt[li*128 + b];
        lcnt[li*128 + b] = (u16)(c + 1);
        p = offs[li] + c;
      } else {
        p = offs[li] + atomicAdd(&cur[li], 1u);
      }
      u32 fl = rs ? 1u : ((t == 0) ? (h0zero ? 1u : 2u) : 0u);
      rows[p] = (u32)t | ((u32)b << 9) | (fl << 16);
      succ[p] = TRASH;
      if (t > 0 && !rs) succ[prev_p] = p - n0;
      prev_p = p;
    }
  }
  __syncthreads();
  // h0 nonzero: prefill hq for list1 rows (fl==2)
  if (!h0zero){
    const u32 c1 = offs[2] - offs[1];
    for (u32 idx = tid; idx < c1 * 512u; idx += 512){
      u32 lpos = offs[1] + (idx >> 9);
      u32 c = idx & 511u;
      u32 b = (rows[lpos] >> 9) & 127u;
      hq[(size_t)(lpos - n0) * 512 + c] = (_Float16)h0[(size_t)b * 512 + c];
    }
  }
}

// ---------------------------------------------------------------------------
// P2: pre-swizzled fp16 W images wimg[jblk][kc 0..15][24576B] + zero flag
// arrays (hflags+xflags = 131072 u32, zeroed by blocks 0..127).
// ---------------------------------------------------------------------------
__global__ void prep_w(const float* __restrict__ Wi, const float* __restrict__ Wh,
                       char* __restrict__ wimg, u32* __restrict__ zflags)
{
  if (blockIdx.x < 128){
    #pragma unroll
    for (int i = 0; i < 4; ++i)
      zflags[blockIdx.x * 1024 + (int)threadIdx.x + i * 256] = 0;
  }
  __shared__ float tile[64][65];
  const int bc = blockIdx.x % 24;
  const int bk = blockIdx.x / 24;
  const int scol0 = (bc % 3) * 512 + (bc / 3) * 64;
  const int k0 = bk * 64;
  #pragma unroll
  for (int i = 0; i < 4; ++i){
    int idx = (int)threadIdx.x + i*256;
    int kk = idx >> 4, c4 = idx & 15;
    int k = k0 + kk;
    const float* src = (k < 512) ? (Wi + (size_t)k*1536 + scol0 + c4*4)
                                 : (Wh + (size_t)(k-512)*1536 + scol0 + c4*4);
    float4 v = *(const float4*)src;
    tile[kk][c4*4+0] = v.x; tile[kk][c4*4+1] = v.y;
    tile[kk][c4*4+2] = v.z; tile[kk][c4*4+3] = v.w;
  }
  __syncthreads();
  const int jb = bc / 3;
  #pragma unroll
  for (int i = 0; i < 4; ++i){
    int idx = (int)threadIdx.x + i*256;
    int cc = idx >> 4, k4 = idx & 15;
    int cimg = (bc % 3)*64 + cc;
    f16x4 c;
    c[0] = (_Float16)tile[k4*4+0][cc]; c[1] = (_Float16)tile[k4*4+1][cc];
    c[2] = (_Float16)tile[k4*4+2][cc]; c[3] = (_Float16)tile[k4*4+3][cc];
    int bby = k4*8;
    int sb = (bby & 8) | ((bby & 0x70) ^ ((cimg & 7) << 4));
    *(f16x4*)(wimg + ((size_t)(jb*16 + bk))*24576 + cimg*128 + sb) = c;
  }
}

// ---------------------------------------------------------------------------
// Fused dataflow kernel: global tile order = [4096 xg tiles][scan levels,
// each level (b,t)-sorted]. Blocks grid-stride in order; readiness via
// hflags (predecessor h, >=8) and xflags (own xg, >=4).
// ---------------------------------------------------------------------------
__global__ __launch_bounds__(256, 2) void gru_fused(
    const float* __restrict__ x, const float* __restrict__ bi,
    const float* __restrict__ bhn, const char* __restrict__ wimg,
    _Float16* __restrict__ xg, _Float16* __restrict__ hq,
    const u32* __restrict__ rows, const u32* __restrict__ off,
    const int* __restrict__ nlists, const u32* __restrict__ succ,
    u32* __restrict__ hflags, u32* __restrict__ xflags,
    float* __restrict__ out)
{
  __shared__ __align__(16) char smem[40960];  // xg: 2x8KB ring | scan: 4x8KB ring + hstage 8KB
  float* ys = out + 65536;
  const u32 n0 = off[1];
  const int tid = threadIdx.x;
  const int lane = tid & 63, wave = tid >> 6;
  const int nblk = (int)gridDim.x;

  // ================= phase 1: xg tiles (pure throughput) =================
  int g = (int)blockIdx.x;
  while (g < NXG){
    const int tm = g >> 2, jp = g & 3;
    g += nblk;

    const float* rp[4];
    #pragma unroll
    for (int i = 0; i < 4; ++i){
      u32 e = rows[tm*64 + (tid>>4) + i*16];
      rp[i] = x + ((size_t)((e & 511u)*128u + ((e >> 9) & 127u)))*512 + (tid & 15)*4;
    }

    f32x4 acc[2][3][4];
    #pragma unroll
    for (int q = 0; q < 2; ++q)
      #pragma unroll
      for (int c = 0; c < 3; ++c)
        #pragma unroll
        for (int m = 0; m < 4; ++m) acc[q][c][m] = (f32x4){0.f,0.f,0.f,0.f};

    float4 areg[4];
    #pragma unroll
    for (int i = 0; i < 4; ++i) areg[i] = *(const float4*)(rp[i]);
    #pragma unroll
    for (int i = 0; i < 4; ++i){
      int r = (tid>>4) + i*16, bby = (tid & 15)*8;
      int sb = (bby & 8) | ((bby & 0x70) ^ ((r & 7) << 4));
      f16x4 c; c[0]=(_Float16)areg[i].x; c[1]=(_Float16)areg[i].y;
               c[2]=(_Float16)areg[i].z; c[3]=(_Float16)areg[i].w;
      *(f16x4*)(smem + r*128 + sb) = c;
    }
    __syncthreads();

    for (int kc = 0; kc < 8; ++kc){
      const int cur = kc & 1;
      if (kc < 7){
        #pragma unroll
        for (int i = 0; i < 4; ++i) areg[i] = *(const float4*)(rp[i] + (kc+1)*64);
      }
      const char* Ab = smem + cur*8192;
      #pragma unroll
      for (int kk = 0; kk < 2; ++kk){
        const int bby = kk*64 + (lane>>4)*16;
        f16x8 af[4];
        #pragma unroll
        for (int mi = 0; mi < 4; ++mi){
          int rr = mi*16 + (lane & 15);
          af[mi] = *(const f16x8*)(Ab + rr*128 + (bby ^ ((rr & 7) << 4)));
        }
        #pragma unroll
        for (int jq = 0; jq < 2; ++jq){
          const char* wp = wimg + ((size_t)((jp*2 + jq)*16 + kc))*24576;
          #pragma unroll
          for (int cls = 0; cls < 3; ++cls){
            int cc = cls*64 + wave*16 + (lane & 15);
            f16x8 wf = *(const f16x8*)(wp + cc*128 + (bby ^ ((cc & 7) << 4)));
            #pragma unroll
            for (int mi = 0; mi < 4; ++mi)
              acc[jq][cls][mi] = __builtin_amdgcn_mfma_f32_16x16x32_f16(af[mi], wf, acc[jq][cls][mi], 0, 0, 0);
          }
        }
      }
      if (kc < 7){
        char* An = smem + (cur^1)*8192;
        #pragma unroll
        for (int i = 0; i < 4; ++i){
          int r = (tid>>4) + i*16, bby = (tid & 15)*8;
          int sb = (bby & 8) | ((bby & 0x70) ^ ((r & 7) << 4));
          f16x4 c; c[0]=(_Float16)areg[i].x; c[1]=(_Float16)areg[i].y;
                   c[2]=(_Float16)areg[i].z; c[3]=(_Float16)areg[i].w;
          *(f16x4*)(An + r*128 + sb) = c;
        }
      }
      __syncthreads();
    }

    // epilogue: C/D layout col=lane&15, row=(lane>>4)*4+reg
    const int jloc = wave*16 + (lane & 15);
    #pragma unroll
    for (int jq = 0; jq < 2; ++jq){
      const int j = (jp*2 + jq)*64 + jloc;
      const float bir = bi[j], biz = bi[512 + j], bin = bi[1024 + j], bh = bhn[j];
      #pragma unroll
      for (int mi = 0; mi < 4; ++mi){
        #pragma unroll
        for (int rg = 0; rg < 4; ++rg){
          int r = mi*16 + (lane >> 4)*4 + rg;
          u32 e = rows[tm*64 + r];
          int tt = (int)(e & 511u), bb = (int)((e >> 9) & 127u);
          float xr = acc[jq][0][mi][rg] + bir;
          float xz = acc[jq][1][mi][rg] + biz;
          float xn = acc[jq][2][mi][rg] + bin;
          if ((e >> 16) == 1u){        // reset/fold row: h = (1-z)*n
            float rr = sigm(xr), zz = sigm(xz);
            float nn = tanh_fast(xn + rr*bh);
            float hv = (1.f - zz)*nn;
            ys[((size_t)(tt*128 + bb))*512 + j] = hv;
            if (tt == 511) out[(size_t)bb*512 + j] = hv;
            u32 sx = succ[tm*64 + r];
            hq[(size_t)sx*512 + j] = (_Float16)hv;
          } else {
            u32 xi = (u32)(tm*64 + r) - n0;
            if (xi >= XGCAP) xi = 0;
            _Float16* p = xg + (size_t)xi*1536 + (jp*2 + jq)*192 + jloc;
            p[0]   = (_Float16)xr;
            p[64]  = (_Float16)xz;
            p[128] = (_Float16)xn;
          }
        }
      }
    }
    __syncthreads();   // all stores drained before flag bumps
    if (tid < 64){
      u32 e = rows[tm*64 + tid];
      if ((e >> 16) == 1u){
        abump(&hflags[(e & 511u)*128u + ((e >> 9) & 127u)], 2u);
      } else {
        abump(&xflags[tm*64 + tid], 1u);
      }
    }
    __syncthreads();
  }

  // ================= phase 2: scan tiles (pipelined dataflow) =================
  const int L = *nlists;
  const double* hqd = (const double*)hq;
  _Float16* hstage = (_Float16*)(smem + 32768);
  int myNext = g - NXG;
  int gt = 0;
  for (int li = 1; li < L; ++li){
    const u32 offA = off[li];
    const int nA = (int)(off[li+1] - offA);
    const int tA = (nA + 63) >> 6;
    const int nt = tA * 8;
    while (myNext < gt + nt){
      const int tile = myNext - gt;
      myNext += nblk;
      const int tm = tile >> 3, jb = tile & 7;
      const u32 rowbase = offA + (u32)tm*64u;
      const u32 xibase = rowbase - n0;
      const int mcount = min(64, nA - tm*64);
      const char* wp = wimg + ((size_t)jb*16 + 8)*24576;
      const int jloc = wave*16 + (lane & 15);

      // ---- wait: wave 0 polls xg readiness (own rows) + h readiness (preds)
      if (wave == 0 && lane < mcount){
        u32 e = rows[rowbase + lane];
        const bool needH = ((e >> 16) == 0u);
        u32 hidx = ((e & 511u) - 1u)*128u + ((e >> 9) & 127u);
        int guard = 0;
        for (;;){
          bool ok = apoll(&xflags[rowbase + lane]) >= 4u;
          if (ok && needH) ok = apoll(&hflags[hidx]) >= 8u;
          if (ok) break;
          __builtin_amdgcn_s_sleep(1);
          if (++guard > (1 << 20)) break;
        }
      }
      __syncthreads();

      // ---- xg prefetch: 48 halves/thread, in flight across the K-pipeline
      _Float16 xgp[3][4][4];
      #pragma unroll
      for (int mi = 0; mi < 4; ++mi){
        #pragma unroll
        for (int rg = 0; rg < 4; ++rg){
          u32 xi = xibase + (u32)(mi*16 + (lane >> 4)*4 + rg);
          if (xi >= XGCAP) xi = 0;
          const _Float16* p = xg + (size_t)xi*1536 + jb*192 + jloc;
          xgp[0][mi][rg] = p[0];
          xgp[1][mi][rg] = p[64];
          xgp[2][mi][rg] = p[128];
        }
      }

      f32x4 acc[3][4];
      #pragma unroll
      for (int c = 0; c < 3; ++c)
        #pragma unroll
        for (int m = 0; m < 4; ++m) acc[c][m] = (f32x4){0.f,0.f,0.f,0.f};
      float hp[4][4];
      double s0[4], s1[4], s2[4];

#define ALOAD(S, CK) do{ \
    const double* p_ = hqd + (size_t)(xibase + (u32)(tid>>2))*128 + (CK)*16 + (tid&3)*4; \
    S[0] = aload(p_); S[1] = aload(p_+1); S[2] = aload(p_+2); S[3] = aload(p_+3); }while(0)

#define AWRITE(S, CK) do{ \
    char* An_ = smem + ((CK) & 3)*8192; \
    int r_ = tid>>2; \
    _Pragma("unroll") for (int i_ = 0; i_ < 4; ++i_){ \
      int bby_ = (tid&3)*32 + i_*8; \
      int sb_ = (bby_ & 8) | ((bby_ & 0x70) ^ ((r_ & 7) << 4)); \
      *(double*)(An_ + r_*128 + sb_) = S[i_]; } }while(0)

#define COMPUTE(KC) do{ \
    const char* Ab_ = smem + ((KC) & 3)*8192; \
    _Pragma("unroll") for (int kk_ = 0; kk_ < 2; ++kk_){ \
      const int bby_ = kk_*64 + (lane>>4)*16; \
      f16x8 af_[4]; \
      _Pragma("unroll") for (int mi_ = 0; mi_ < 4; ++mi_){ \
        int rr_ = mi_*16 + (lane & 15); \
        af_[mi_] = *(const f16x8*)(Ab_ + rr_*128 + (bby_ ^ ((rr_ & 7) << 4))); } \
      _Pragma("unroll") for (int cl_ = 0; cl_ < 3; ++cl_){ \
        int cc_ = cl_*64 + wave*16 + (lane & 15); \
        f16x8 wf_ = *(const f16x8*)(wp + (size_t)(KC)*24576 + cc_*128 + (bby_ ^ ((cc_ & 7) << 4))); \
        _Pragma("unroll") for (int mi_ = 0; mi_ < 4; ++mi_) \
          acc[cl_][mi_] = __builtin_amdgcn_mfma_f32_16x16x32_f16(af_[mi_], wf_, acc[cl_][mi_], 0, 0, 0); } } \
    if ((KC) == jb){ \
      const int bb2_ = jloc*2; \
      _Pragma("unroll") for (int mi_ = 0; mi_ < 4; ++mi_) \
        _Pragma("unroll") for (int rg_ = 0; rg_ < 4; ++rg_){ \
          int r2_ = mi_*16 + (lane >> 4)*4 + rg_; \
          int sb2_ = (bb2_ & 0x0F) | ((bb2_ & 0x70) ^ ((r2_ & 7) << 4)); \
          hp[mi_][rg_] = (float)(*(const _Float16*)(Ab_ + r2_*128 + sb2_)); } } }while(0)

      // prologue: 3 chunk-loads in flight, write chunk 0
      ALOAD(s0, 0); ALOAD(s1, 1); ALOAD(s2, 2);
      AWRITE(s0, 0);
      __syncthreads();
      // steady: load k+3 | compute k | write k+1 | barrier
      ALOAD(s0, 3); COMPUTE(0); AWRITE(s1, 1); __syncthreads();
      ALOAD(s1, 4); COMPUTE(1); AWRITE(s2, 2); __syncthreads();
      ALOAD(s2, 5); COMPUTE(2); AWRITE(s0, 3); __syncthreads();
      ALOAD(s0, 6); COMPUTE(3); AWRITE(s1, 4); __syncthreads();
      ALOAD(s1, 7); COMPUTE(4); AWRITE(s2, 5); __syncthreads();
                    COMPUTE(5); AWRITE(s0, 6); __syncthreads();
                    COMPUTE(6); AWRITE(s1, 7); __syncthreads();
                    COMPUTE(7);
#undef ALOAD
#undef AWRITE
#undef COMPUTE

      // epilogue: gates + h_new -> ys/out (plain) + hstage (LDS)
      const int j = jb*64 + jloc;
      const float bh = bhn[j];
      #pragma unroll
      for (int mi = 0; mi < 4; ++mi){
        #pragma unroll
        for (int rg = 0; rg < 4; ++rg){
          int r = mi*16 + (lane >> 4)*4 + rg;
          float rr = sigm((float)xgp[0][mi][rg] + acc[0][mi][rg]);
          float zz = sigm((float)xgp[1][mi][rg] + acc[1][mi][rg]);
          float nn = tanh_fast((float)xgp[2][mi][rg] + rr*(acc[2][mi][rg] + bh));
          float hv = (1.f - zz)*nn + zz*hp[mi][rg];
          hstage[r*64 + jloc] = (_Float16)hv;
          if (r < mcount){
            u32 e = rows[rowbase + r];
            int tt = (int)(e & 511u), bb = (int)((e >> 9) & 127u);
            ys[((size_t)(tt*128 + bb))*512 + j] = hv;
            if (tt == 511) out[(size_t)bb*512 + j] = hv;
          }
        }
      }
      __syncthreads();
      // coalesced hq write: 4 threads/row stream 128B via 8B agent atomics;
      // dead chains (succ==TRASH) skipped
      {
        int row = tid >> 2;
        if (row < mcount){
          u32 sx = succ[rowbase + row];
          if (sx != TRASH){
            const u64* src = (const u64*)(hstage + row*64) + (tid & 3)*4;
            u64* dst = (u64*)hq + (size_t)sx*128 + jb*16 + (tid & 3)*4;
            astore64(dst+0, src[0]); astore64(dst+1, src[1]);
            astore64(dst+2, src[2]); astore64(dst+3, src[3]);
          }
        }
      }
      __syncthreads();   // vmcnt(0) drained -> hq stores at coherence point
      if (tid < mcount && succ[rowbase + tid] != TRASH){
        u32 e = rows[rowbase + tid];
        abump(&hflags[(e & 511u)*128u + ((e >> 9) & 127u)], 1u);
      }
    }
    gt += nt;
  }
}

// ---------------------------------------------------------------------------
extern "C" void kernel_launch(void* const* d_in, const int* in_sizes, int n_in,
                              void* d_out, int out_size, void* d_ws, size_t ws_size,
                              hipStream_t stream)
{
  const float* x  = (const float*)d_in[0];
  const void*  resets = d_in[1];
  const float* h0 = (const float*)d_in[2];
  const float* Wi = (const float*)d_in[3];
  const float* bi = (const float*)d_in[4];
  const float* Wh = (const float*)d_in[5];
  const float* bhn= (const float*)d_in[6];
  float* out = (float*)d_out;

  char* ws = (char*)d_ws;
  u32* off    = (u32*)ws;                       // 521 u32
  int* nlists = (int*)(ws + 4096);
  u32* rows   = (u32*)(ws + 8192);              // 65600 u32
  u32* hflags = (u32*)(ws + 294912);            // 65536 u32
  u32* xflags = (u32*)(ws + 557056);            // 65536 u32
  u32* succ   = (u32*)(ws + 819200);            // 65600 u32
  char* wimg  = ws + 1081600;                   // 3.07 MB
  _Float16* xg = (_Float16*)(ws + 4325376);     // XGCAP*1536 fp16 = 105.4 MB
  _Float16* hq = (_Float16*)(ws + 109707264);   // XGCAP*512 fp16 = 35.1 MB

  prep_lists<<<dim3(1), dim3(512), 0, stream>>>(resets, h0, rows, off, nlists, succ, hq);
  prep_w<<<dim3(384), dim3(256), 0, stream>>>(Wi, Wh, wimg, hflags);

  // co-residency guarantee for the spin-wait dataflow
  int perCU = 0;
  (void)hipOccupancyMaxActiveBlocksPerMultiprocessor(&perCU, gru_fused, 256, 0);
  if (perCU < 1) perCU = 1;
  int grid = perCU * 256;
  if (grid > 1024) grid = 1024;

  void* args[] = {(void*)&x, (void*)&bi, (void*)&bhn, (void*)&wimg,
                  (void*)&xg, (void*)&hq, (void*)&rows, (void*)&off,
                  (void*)&nlists, (void*)&succ, (void*)&hflags, (void*)&xflags,
                  (void*)&out};
  hipLaunchCooperativeKernel(gru_fused, dim3(grid), dim3(256), args, 0, stream);

  (void)in_sizes; (void)n_in; (void)out_size; (void)ws_size;
}

// Round 11
// 1010.505 us; speedup vs baseline: 1.1374x; 1.1374x over previous
//
#include <hip/hip_runtime.h>

typedef __attribute__((ext_vector_type(4))) float f32x4;
typedef __attribute__((ext_vector_type(8))) _Float16 f16x8;
typedef __attribute__((ext_vector_type(4))) _Float16 f16x4;
typedef unsigned short u16;
typedef unsigned int u32;
typedef unsigned long long u64;

#define XGCAP 34304           // rows with stored xg (non-reset ~32832, 12-sigma margin)
#define NXG 4096              // phase-1 tiles: 512 tm (128 rows) x 8 jb (192 cols)

__device__ __forceinline__ float sigm(float v){ return 1.0f / (1.0f + __expf(-v)); }
__device__ __forceinline__ float tanh_fast(float v){
  v = fminf(15.0f, fmaxf(-15.0f, v));
  float e = __expf(2.0f * v);
  return (e - 1.0f) / (e + 1.0f);
}
__device__ __forceinline__ void gload16(const void* g, void* l){
  __builtin_amdgcn_global_load_lds((const __attribute__((address_space(1))) void*)g,
                                   (__attribute__((address_space(3))) void*)l, 16, 0, 0);
}
// agent-scope atomics: coherent at L3, no cache-invalidating fences
__device__ __forceinline__ double aload(const double* p){
  return __hip_atomic_load(p, __ATOMIC_RELAXED, __HIP_MEMORY_SCOPE_AGENT);
}
__device__ __forceinline__ void astore(float* p, float v){
  __hip_atomic_store(p, v, __ATOMIC_RELAXED, __HIP_MEMORY_SCOPE_AGENT);
}
__device__ __forceinline__ u32 apoll(const u32* p){
  return __hip_atomic_load(p, __ATOMIC_RELAXED, __HIP_MEMORY_SCOPE_AGENT);
}
__device__ __forceinline__ void abump(u32* p, u32 v){
  __hip_atomic_fetch_add(p, v, __ATOMIC_RELAXED, __HIP_MEMORY_SCOPE_AGENT);
}
__device__ __forceinline__ float2 d2f2(double d){ union{double d; float2 f;} u; u.d = d; return u.f; }

// ---------------------------------------------------------------------------
// P1: depth-ordered row lists, each level sorted by (b,t). One block, 512 thr.
// resets staged to an LDS bitmap (ballot-pack); per-(level,b) LDS u16 counters
// (no atomic storms). rows[] entry: t | b<<9 | fl<<16 (0=wait, 1=xg-handled,
// 2=h0). If h0==0 (sniffed), t0 non-reset rows fold into list0.
// ---------------------------------------------------------------------------
__global__ __launch_bounds__(512) void prep_lists(
    const void* __restrict__ resets_raw, const float* __restrict__ h0,
    u32* __restrict__ rows, u32* __restrict__ off, int* __restrict__ nlists)
{
  __shared__ u32 bitmap[2048];
  __shared__ u16 lcnt[127*128];
  __shared__ u32 cnt[520];
  __shared__ u32 offs[521];
  __shared__ u32 cur[520];
  __shared__ int is_bytes, h0nz;
  const int tid = threadIdx.x;
  const int lane = tid & 63, wave = tid >> 6;
  for (int i = tid; i < 2048; i += 512) bitmap[i] = 0;
  for (int i = tid; i < 127*128; i += 512) lcnt[i] = 0;
  for (int i = tid; i < 520; i += 512){ cnt[i] = 0; cur[i] = 0; }
  if (tid == 0){ is_bytes = 0; h0nz = 0; }
  for (int i = tid; i < 64; i += 512) rows[65536 + i] = (2u << 16); // pad: no wait
  __syncthreads();
  { // resets dtype sniff
    const u32* w = (const u32*)resets_raw;
    int bad = 0;
    for (int i = tid; i < 4096; i += 512) bad |= (w[i] > 1u);
    if (bad) atomicOr(&is_bytes, 1);
  }
  { // h0 == 0 sniff
    const u32* hw = (const u32*)h0;
    u32 o = 0;
    for (int i = tid; i < 65536; i += 512) o |= hw[i];
    if (o) atomicOr(&h0nz, 1);
  }
  __syncthreads();
  const bool h0zero = (h0nz == 0);
  if (is_bytes){
    const u32* wb = (const u32*)resets_raw;
    for (int i = tid; i < 16384; i += 512){
      u32 v = wb[i];
      u32 bits = ((v & 0xFFu) ? 1u : 0u) | (((v >> 8) & 0xFFu) ? 2u : 0u)
               | (((v >> 16) & 0xFFu) ? 4u : 0u) | (((v >> 24) & 0xFFu) ? 8u : 0u);
      if (bits) atomicOr(&bitmap[i >> 3], bits << ((i & 7) * 4));
    }
  } else {
    const u32* w = (const u32*)resets_raw;
    for (int r = 0; r < 128; ++r){
      u32 v = w[r * 512 + tid];
      u64 m = __ballot(v != 0u);
      if (lane == 0){
        int idx = r * 16 + wave * 2;
        bitmap[idx] = (u32)m; bitmap[idx + 1] = (u32)(m >> 32);
      }
    }
  }
  __syncthreads();
  if (tid < 128){
    const int b = tid;
    int depth = 0;
    for (int t = 0; t < 512; ++t){
      int pos = t * 128 + b;
      bool rs = (bitmap[pos >> 5] >> (pos & 31)) & 1u;
      depth = rs ? 0 : ((t == 0) ? 0 : depth + 1);
      int li = (depth == 0) ? ((rs || h0zero) ? 0 : 1) : (depth + 1);
      if (li < 127) lcnt[li*128 + b]++;
      else atomicAdd(&cnt[li], 1u);
    }
  }
  __syncthreads();
  if (tid < 127){
    const int li = tid;
    u32 s = 0;
    for (int b = 0; b < 128; ++b){
      u32 v = lcnt[li*128 + b];
      lcnt[li*128 + b] = (u16)s;
      s += v;
    }
    cnt[li] = s;
  }
  __syncthreads();
  if (tid == 0){
    u32 s = 0; int mx = 0;
    for (int i = 0; i < 520; ++i){
      offs[i] = s; s += cnt[i];
      if (cnt[i]) mx = i;
    }
    offs[520] = s;
    *nlists = mx + 1;
  }
  __syncthreads();
  for (int i = tid; i < 521; i += 512) off[i] = offs[i];
  __syncthreads();
  if (tid < 128){
    const int b = tid;
    int depth = 0;
    for (int t = 0; t < 512; ++t){
      int pos = t * 128 + b;
      bool rs = (bitmap[pos >> 5] >> (pos & 31)) & 1u;
      depth = rs ? 0 : ((t == 0) ? 0 : depth + 1);
      int li = (depth == 0) ? ((rs || h0zero) ? 0 : 1) : (depth + 1);
      u32 p;
      if (li < 127){
        u16 c = lcnt[li*128 + b];
        lcnt[li*128 + b] = (u16)(c + 1);
        p = offs[li] + c;
      } else {
        p = offs[li] + atomicAdd(&cur[li], 1u);
      }
      u32 fl = rs ? 1u : ((t == 0) ? (h0zero ? 1u : 2u) : 0u);
      rows[p] = (u32)t | ((u32)b << 9) | (fl << 16);
    }
  }
}

// ---------------------------------------------------------------------------
// P2: pre-swizzled fp16 W images wimg[jblk][kc 0..15][24576B] + zero both
// flag arrays (128 KB contiguous, blocks 0..127).
// ---------------------------------------------------------------------------
__global__ void prep_w(const float* __restrict__ Wi, const float* __restrict__ Wh,
                       char* __restrict__ wimg, u32* __restrict__ zflags)
{
  if (blockIdx.x < 128){
    #pragma unroll
    for (int i = 0; i < 4; ++i)
      zflags[blockIdx.x * 1024 + (int)threadIdx.x + i * 256] = 0;
  }
  __shared__ float tile[64][65];
  const int bc = blockIdx.x % 24;
  const int bk = blockIdx.x / 24;
  const int scol0 = (bc % 3) * 512 + (bc / 3) * 64;
  const int k0 = bk * 64;
  #pragma unroll
  for (int i = 0; i < 4; ++i){
    int idx = (int)threadIdx.x + i*256;
    int kk = idx >> 4, c4 = idx & 15;
    int k = k0 + kk;
    const float* src = (k < 512) ? (Wi + (size_t)k*1536 + scol0 + c4*4)
                                 : (Wh + (size_t)(k-512)*1536 + scol0 + c4*4);
    float4 v = *(const float4*)src;
    tile[kk][c4*4+0] = v.x; tile[kk][c4*4+1] = v.y;
    tile[kk][c4*4+2] = v.z; tile[kk][c4*4+3] = v.w;
  }
  __syncthreads();
  const int jb = bc / 3;
  #pragma unroll
  for (int i = 0; i < 4; ++i){
    int idx = (int)threadIdx.x + i*256;
    int cc = idx >> 4, k4 = idx & 15;
    int cimg = (bc % 3)*64 + cc;
    f16x4 c;
    c[0] = (_Float16)tile[k4*4+0][cc]; c[1] = (_Float16)tile[k4*4+1][cc];
    c[2] = (_Float16)tile[k4*4+2][cc]; c[3] = (_Float16)tile[k4*4+3][cc];
    int bby = k4*8;
    int sb = (bby & 8) | ((bby & 0x70) ^ ((cimg & 7) << 4));
    *(f16x4*)(wimg + ((size_t)(jb*16 + bk))*24576 + cimg*128 + sb) = c;
  }
}

// ---------------------------------------------------------------------------
// P3: gather-convert x -> xq fp16 [65536 rows][1024 B], list-ordered and
// PRE-SWIZZLED per 128-B chunk (so phase-1 DMA-linear LDS + swizzled ds_read
// sees the standard layout). 16 rows/block, coalesced reads/writes.
// ---------------------------------------------------------------------------
__global__ __launch_bounds__(256) void prep_x(
    const float* __restrict__ x, const u32* __restrict__ rows,
    char* __restrict__ xq)
{
  const int tid = threadIdx.x;
  const u32 lpos = blockIdx.x * 16 + (tid >> 4);
  const u32 e = rows[lpos];
  const float* src = x + ((size_t)((e & 511u)*128u + ((e >> 9) & 127u)))*512;
  const int lane16 = tid & 15;
  char* dst = xq + (size_t)lpos * 1024;
  const int swzr = ((int)lpos & 7) << 4;
  #pragma unroll
  for (int it = 0; it < 8; ++it){
    float4 v = *(const float4*)(src + it*64 + lane16*4);
    f16x4 c; c[0]=(_Float16)v.x; c[1]=(_Float16)v.y;
             c[2]=(_Float16)v.z; c[3]=(_Float16)v.w;
    int bby = lane16 * 8;
    int sb = (bby & 8) | ((bby & 0x70) ^ swzr);
    *(f16x4*)(dst + it*128 + sb) = c;
  }
}

// ---------------------------------------------------------------------------
// Fused: phase 1 = m97-style DMA GEMM (128x192 tiles, A+W via global_load_lds
// double-buffered); phase 2 = R5-structure scan dataflow (ys f32 via agent
// atomics, 4-deep LDS ring). Readiness: hflags>=8 (pred h), xflags>=8 (own xg).
// ---------------------------------------------------------------------------
__global__ __launch_bounds__(256, 2) void gru_fused(
    const char* __restrict__ xq, const float* __restrict__ bi,
    const float* __restrict__ bhn, const char* __restrict__ wimg,
    const float* __restrict__ h0, _Float16* __restrict__ xg,
    const u32* __restrict__ rows, const u32* __restrict__ off,
    const int* __restrict__ nlists, u32* __restrict__ hflags,
    u32* __restrict__ xflags, float* __restrict__ out)
{
  __shared__ __align__(16) char smem[81920];  // ph1: A 2x16K | W 2x24K @32768; ph2: ring 4x8K
  float* ys = out + 65536;
  const u32 n0 = off[1];
  const int tid = threadIdx.x;
  const int lane = tid & 63, wave = tid >> 6;
  const int nblk = (int)gridDim.x;

  // ================= phase 1: xg GEMM tiles (full DMA staging) =============
  int g = (int)blockIdx.x;
  while (g < NXG){
    const int tm = g >> 3, jb = g & 7;
    g += nblk;
    const char* asrc = xq + (size_t)tm * 131072;          // 128 rows x 1024 B
    const char* wsrc = wimg + ((size_t)jb * 16) * 24576;

    f32x4 acc[3][8];
    #pragma unroll
    for (int c = 0; c < 3; ++c)
      #pragma unroll
      for (int m = 0; m < 8; ++m) acc[c][m] = (f32x4){0.f,0.f,0.f,0.f};

#define DMA_A(KC, BUF) do{ \
    char* l_ = smem + (BUF)*16384 + wave*4096; \
    const char* g_ = asrc + (size_t)(wave*32 + (lane>>3))*1024 + (KC)*128 + (lane&7)*16; \
    _Pragma("unroll") for (int i_ = 0; i_ < 4; ++i_) \
      gload16(g_ + i_*8192, l_ + i_*1024); }while(0)
#define DMA_W(KC, BUF) do{ \
    char* l_ = smem + 32768 + (BUF)*24576 + wave*6144; \
    const char* g_ = wsrc + (size_t)(KC)*24576 + wave*6144 + lane*16; \
    _Pragma("unroll") for (int i_ = 0; i_ < 6; ++i_) \
      gload16(g_ + i_*1024, l_ + i_*1024); }while(0)

    DMA_A(0, 0); DMA_W(0, 0);
    __syncthreads();
    for (int kc = 0; kc < 8; ++kc){
      const int cur = kc & 1;
      if (kc < 7){ DMA_A(kc+1, cur^1); DMA_W(kc+1, cur^1); }
      const char* Ab = smem + cur*16384;
      const char* Wb = smem + 32768 + cur*24576;
      #pragma unroll
      for (int kk = 0; kk < 2; ++kk){
        const int bby = kk*64 + (lane>>4)*16;
        f16x8 af[8];
        #pragma unroll
        for (int mi = 0; mi < 8; ++mi){
          int rr = mi*16 + (lane & 15);
          af[mi] = *(const f16x8*)(Ab + rr*128 + (bby ^ ((rr & 7) << 4)));
        }
        #pragma unroll
        for (int cls = 0; cls < 3; ++cls){
          int cc = cls*64 + wave*16 + (lane & 15);
          f16x8 wf = *(const f16x8*)(Wb + cc*128 + (bby ^ ((cc & 7) << 4)));
          #pragma unroll
          for (int mi = 0; mi < 8; ++mi)
            acc[cls][mi] = __builtin_amdgcn_mfma_f32_16x16x32_f16(af[mi], wf, acc[cls][mi], 0, 0, 0);
        }
      }
      __syncthreads();
    }
#undef DMA_A
#undef DMA_W

    // epilogue: C/D layout col=lane&15, row=(lane>>4)*4+reg
    const int jloc = wave*16 + (lane & 15);
    const int j = jb*64 + jloc;
    const float bir = bi[j], biz = bi[512 + j], bin = bi[1024 + j], bh = bhn[j];
    #pragma unroll
    for (int mi = 0; mi < 8; ++mi){
      #pragma unroll
      for (int rg = 0; rg < 4; ++rg){
        int r = mi*16 + (lane >> 4)*4 + rg;
        u32 e = rows[tm*128 + r];
        int tt = (int)(e & 511u), bb = (int)((e >> 9) & 127u);
        float xr = acc[0][mi][rg] + bir;
        float xz = acc[1][mi][rg] + biz;
        float xn = acc[2][mi][rg] + bin;
        if ((e >> 16) == 1u){        // reset/fold row: h = (1-z)*n
          float rr = sigm(xr), zz = sigm(xz);
          float nn = tanh_fast(xn + rr*bh);
          float hv = (1.f - zz)*nn;
          ys[((size_t)(tt*128 + bb))*512 + j] = hv;
          if (tt == 511) out[(size_t)bb*512 + j] = hv;
        } else {
          u32 xi = (u32)(tm*128 + r) - n0;
          if (xi >= XGCAP) xi = 0;
          _Float16* p = xg + (size_t)xi*1536 + jb*192 + jloc;
          p[0]   = (_Float16)xr;
          p[64]  = (_Float16)xz;
          p[128] = (_Float16)xn;
        }
      }
    }
    __syncthreads();   // all stores drained before flag bumps
    if (tid < 128){
      u32 e = rows[tm*128 + tid];
      if ((e >> 16) == 1u) abump(&hflags[(e & 511u)*128u + ((e >> 9) & 127u)], 1u);
      else                 abump(&xflags[tm*128 + tid], 1u);
    }
    __syncthreads();
  }

  // ================= phase 2: scan tiles (R5 dataflow) =====================
  const int L = *nlists;
  int myNext = g - NXG;
  int gt = 0;
  for (int li = 1; li < L; ++li){
    const u32 offA = off[li];
    const int nA = (int)(off[li+1] - offA);
    const int tA = (nA + 63) >> 6;
    const int nt = tA * 8;
    while (myNext < gt + nt){
      const int tile = myNext - gt;
      myNext += nblk;
      const int tm = tile >> 3, jb = tile & 7;
      const u32 rowbase = offA + (u32)tm*64u;
      const u32 xibase = rowbase - n0;
      const int mcount = min(64, nA - tm*64);
      const char* wp = wimg + ((size_t)jb*16 + 8)*24576;
      const int jloc = wave*16 + (lane & 15);

      // wait: wave 0 polls xg readiness (own rows) + h readiness (preds)
      if (wave == 0 && lane < mcount){
        u32 e = rows[rowbase + lane];
        const bool needH = ((e >> 16) == 0u);
        u32 hidx = ((e & 511u) - 1u)*128u + ((e >> 9) & 127u);
        int guard = 0;
        for (;;){
          bool ok = apoll(&xflags[rowbase + lane]) >= 8u;
          if (ok && needH) ok = apoll(&hflags[hidx]) >= 8u;
          if (ok) break;
          __builtin_amdgcn_s_sleep(1);
          if (++guard > (1 << 20)) break;
        }
      }
      __syncthreads();

      const float* rp[4];
      #pragma unroll
      for (int i = 0; i < 4; ++i){
        u32 e = rows[rowbase + (tid>>4) + i*16];
        int tt = (int)(e & 511u), bb = (int)((e >> 9) & 127u);
        const float* base = ((e >> 16) == 0u) ? (ys + ((size_t)((tt-1)*128 + bb))*512)
                                              : (h0 + (size_t)bb*512);
        rp[i] = base + (tid & 15)*4;
      }

      // xg prefetch: 48 halves/thread, in flight across the K-pipeline
      _Float16 xgp[3][4][4];
      #pragma unroll
      for (int mi = 0; mi < 4; ++mi){
        #pragma unroll
        for (int rg = 0; rg < 4; ++rg){
          u32 xi = xibase + (u32)(mi*16 + (lane >> 4)*4 + rg);
          if (xi >= XGCAP) xi = 0;
          const _Float16* p = xg + (size_t)xi*1536 + jb*192 + jloc;
          xgp[0][mi][rg] = p[0];
          xgp[1][mi][rg] = p[64];
          xgp[2][mi][rg] = p[128];
        }
      }

      f32x4 acc[3][4];
      #pragma unroll
      for (int c = 0; c < 3; ++c)
        #pragma unroll
        for (int m = 0; m < 4; ++m) acc[c][m] = (f32x4){0.f,0.f,0.f,0.f};
      float hp[4][4];
      double s0[4][2], s1[4][2], s2[4][2];

#define ALOAD(S, CK) do{ \
    _Pragma("unroll") for (int i_ = 0; i_ < 4; ++i_){ \
      const double* p_ = (const double*)(rp[i_] + (CK)*64); \
      S[i_][0] = aload(p_); S[i_][1] = aload(p_ + 1); } }while(0)

#define AWRITE(S, CK) do{ \
    char* An_ = smem + ((CK) & 3)*8192; \
    _Pragma("unroll") for (int i_ = 0; i_ < 4; ++i_){ \
      float2 u0_ = d2f2(S[i_][0]), u1_ = d2f2(S[i_][1]); \
      int r_ = (tid>>4) + i_*16, bby_ = (tid & 15)*8; \
      int sb_ = (bby_ & 8) | ((bby_ & 0x70) ^ ((r_ & 7) << 4)); \
      f16x4 c_; c_[0]=(_Float16)u0_.x; c_[1]=(_Float16)u0_.y; \
                c_[2]=(_Float16)u1_.x; c_[3]=(_Float16)u1_.y; \
      *(f16x4*)(An_ + r_*128 + sb_) = c_; } }while(0)

#define COMPUTE(KC) do{ \
    const char* Ab_ = smem + ((KC) & 3)*8192; \
    _Pragma("unroll") for (int kk_ = 0; kk_ < 2; ++kk_){ \
      const int bby_ = kk_*64 + (lane>>4)*16; \
      f16x8 af_[4]; \
      _Pragma("unroll") for (int mi_ = 0; mi_ < 4; ++mi_){ \
        int rr_ = mi_*16 + (lane & 15); \
        af_[mi_] = *(const f16x8*)(Ab_ + rr_*128 + (bby_ ^ ((rr_ & 7) << 4))); } \
      _Pragma("unroll") for (int cl_ = 0; cl_ < 3; ++cl_){ \
        int cc_ = cl_*64 + wave*16 + (lane & 15); \
        f16x8 wf_ = *(const f16x8*)(wp + (size_t)(KC)*24576 + cc_*128 + (bby_ ^ ((cc_ & 7) << 4))); \
        _Pragma("unroll") for (int mi_ = 0; mi_ < 4; ++mi_) \
          acc[cl_][mi_] = __builtin_amdgcn_mfma_f32_16x16x32_f16(af_[mi_], wf_, acc[cl_][mi_], 0, 0, 0); } } \
    if ((KC) == jb){ \
      const int bb2_ = jloc*2; \
      _Pragma("unroll") for (int mi_ = 0; mi_ < 4; ++mi_) \
        _Pragma("unroll") for (int rg_ = 0; rg_ < 4; ++rg_){ \
          int r2_ = mi_*16 + (lane >> 4)*4 + rg_; \
          int sb2_ = (bb2_ & 0x0F) | ((bb2_ & 0x70) ^ ((r2_ & 7) << 4)); \
          hp[mi_][rg_] = (float)(*(const _Float16*)(Ab_ + r2_*128 + sb2_)); } } }while(0)

      ALOAD(s0, 0); ALOAD(s1, 1); ALOAD(s2, 2);
      AWRITE(s0, 0);
      __syncthreads();
      ALOAD(s0, 3); COMPUTE(0); AWRITE(s1, 1); __syncthreads();
      ALOAD(s1, 4); COMPUTE(1); AWRITE(s2, 2); __syncthreads();
      ALOAD(s2, 5); COMPUTE(2); AWRITE(s0, 3); __syncthreads();
      ALOAD(s0, 6); COMPUTE(3); AWRITE(s1, 4); __syncthreads();
      ALOAD(s1, 7); COMPUTE(4); AWRITE(s2, 5); __syncthreads();
                    COMPUTE(5); AWRITE(s0, 6); __syncthreads();
                    COMPUTE(6); AWRITE(s1, 7); __syncthreads();
                    COMPUTE(7);
#undef ALOAD
#undef AWRITE
#undef COMPUTE

      // epilogue: gates + h_new -> ys (agent stores) + out for t=511
      const int j = jb*64 + jloc;
      const float bh = bhn[j];
      #pragma unroll
      for (int mi = 0; mi < 4; ++mi){
        #pragma unroll
        for (int rg = 0; rg < 4; ++rg){
          int r = mi*16 + (lane >> 4)*4 + rg;
          if (r < mcount){
            u32 e = rows[rowbase + r];
            int tt = (int)(e & 511u), bb = (int)((e >> 9) & 127u);
            float rr = sigm((float)xgp[0][mi][rg] + acc[0][mi][rg]);
            float zz = sigm((float)xgp[1][mi][rg] + acc[1][mi][rg]);
            float nn = tanh_fast((float)xgp[2][mi][rg] + rr*(acc[2][mi][rg] + bh));
            float hv = (1.f - zz)*nn + zz*hp[mi][rg];
            astore(&ys[((size_t)(tt*128 + bb))*512 + j], hv);
            if (tt == 511) out[(size_t)bb*512 + j] = hv;
          }
        }
      }
      __syncthreads();   // vmcnt(0) drained -> ys stores at coherence point
      if (tid < mcount){
        u32 e = rows[rowbase + tid];
        abump(&hflags[(e & 511u)*128u + ((e >> 9) & 127u)], 1u);
      }
    }
    gt += nt;
  }
}

// ---------------------------------------------------------------------------
extern "C" void kernel_launch(void* const* d_in, const int* in_sizes, int n_in,
                              void* d_out, int out_size, void* d_ws, size_t ws_size,
                              hipStream_t stream)
{
  const float* x  = (const float*)d_in[0];
  const void*  resets = d_in[1];
  const float* h0 = (const float*)d_in[2];
  const float* Wi = (const float*)d_in[3];
  const float* bi = (const float*)d_in[4];
  const float* Wh = (const float*)d_in[5];
  const float* bhn= (const float*)d_in[6];
  float* out = (float*)d_out;

  char* ws = (char*)d_ws;
  u32* off    = (u32*)ws;                       // 521 u32
  int* nlists = (int*)(ws + 4096);
  u32* rows   = (u32*)(ws + 8192);              // 65600 u32
  u32* hflags = (u32*)(ws + 294912);            // 65536 u32
  u32* xflags = (u32*)(ws + 557056);            // 65536 u32 (contiguous after hflags)
  char* wimg  = ws + 819200;                    // 3.07 MB -> ends 3,964,928
  char* xq    = ws + 4194304;                   // 65536*1024 B = 67.1 MB -> ends 71,303,168
  _Float16* xg = (_Float16*)(ws + 71303168);    // XGCAP*1536 fp16 = 105.4 MB -> ~176.7 MB

  prep_lists<<<dim3(1), dim3(512), 0, stream>>>(resets, h0, rows, off, nlists);
  prep_w<<<dim3(384), dim3(256), 0, stream>>>(Wi, Wh, wimg, hflags);
  prep_x<<<dim3(4096), dim3(256), 0, stream>>>(x, rows, xq);

  // co-residency guarantee for the spin-wait dataflow
  int perCU = 0;
  (void)hipOccupancyMaxActiveBlocksPerMultiprocessor(&perCU, gru_fused, 256, 0);
  if (perCU < 1) perCU = 1;
  int grid = perCU * 256;
  if (grid > 1024) grid = 1024;

  void* args[] = {(void*)&xq, (void*)&bi, (void*)&bhn, (void*)&wimg,
                  (void*)&h0, (void*)&xg, (void*)&rows, (void*)&off,
                  (void*)&nlists, (void*)&hflags, (void*)&xflags, (void*)&out};
  hipLaunchCooperativeKernel(gru_fused, dim3(grid), dim3(256), args, 0, stream);

  (void)in_sizes; (void)n_in; (void)out_size; (void)ws_size;
}